// Round 2
// baseline (6485.181 us; speedup 1.0000x reference)
//
#include <hip/hip_runtime.h>

// Recurrent spiking LIF network: T=64, B=32, NE=4096, NI=1024, N=5120.
// Spikes are exactly {0,1} (surrogate fn is exactly binary in forward), so
// each synaptic current is a subset-sum of fp32 weights. We accumulate in
// FP64 and keep v in FP64 so our trajectory matches the float64 numpy
// reference to ~1e-13 -- no spike flips from summation-order noise.
//
// Per step: mv64 (k-split matvec, fp64 partials in ws) + upd64 (LIF update).
// Workspace cascade: G (k-split) chosen from ws_size, identical every call.

#define NE 4096
#define NI 1024
#define NN 5120
#define BB 32
#define CHUNK 160      // k-elements per staged chunk
#define NCHUNKS 32     // NN / CHUNK

// ---------------- matvec partial kernel (fp64 accumulation) ----------------
// grid: (NN/256, G). block: 256 threads. Each thread owns target neuron n,
// accumulates acc[32] (all batches) over NC=NCHUNKS/G chunks of CHUNK sources.
template <int NC>
__global__ __launch_bounds__(256) void mv64_kernel(
    const float* __restrict__ W_ee, const float* __restrict__ W_ei,
    const float* __restrict__ W_ie, const float* __restrict__ W_ii,
    const float* __restrict__ s,     // [BB][NN] current spikes (0.0/1.0)
    double* __restrict__ partial)    // [G][BB][NN]
{
    __shared__ float s_l[BB][CHUNK];
    const int n = blockIdx.x * 256 + threadIdx.x;   // 0..NN-1

    double acc[BB];
#pragma unroll
    for (int j = 0; j < BB; ++j) acc[j] = 0.0;

    const bool isE = (n < NE);
    const int nr = isE ? n : n - NE;
    const float* __restrict__ rowA = isE ? (W_ee + (size_t)nr * NE) : (W_ei + (size_t)nr * NE);
    const float* __restrict__ rowB = isE ? (W_ie + (size_t)nr * NI) : (W_ii + (size_t)nr * NI);

    for (int c = 0; c < NC; ++c) {
        const int kbase = (blockIdx.y * NC + c) * CHUNK;

        if (c) __syncthreads();   // protect s_l overwrite
        for (int ii = threadIdx.x; ii < BB * CHUNK; ii += 256) {
            int j = ii / CHUNK;
            int kk = ii - j * CHUNK;
            s_l[j][kk] = s[j * NN + kbase + kk];
        }
        __syncthreads();

        int aEnd = NE - kbase;               // E/I boundary inside chunk
        if (aEnd < 0) aEnd = 0;
        if (aEnd > CHUNK) aEnd = CHUNK;      // always a multiple of 4 here

        for (int kk = 0; kk < aEnd; kk += 4) {
            const float4 w = *reinterpret_cast<const float4*>(rowA + kbase + kk);
            const double w0 = w.x, w1 = w.y, w2 = w.z, w3 = w.w;
#pragma unroll
            for (int j = 0; j < BB; ++j) {
                const float4 sv = *reinterpret_cast<const float4*>(&s_l[j][kk]);
                acc[j] += w0 * (double)sv.x + w1 * (double)sv.y
                        + w2 * (double)sv.z + w3 * (double)sv.w;
            }
        }
        for (int kk = aEnd; kk < CHUNK; kk += 4) {
            const float4 w = *reinterpret_cast<const float4*>(rowB + (kbase + kk - NE));
            const double w0 = w.x, w1 = w.y, w2 = w.z, w3 = w.w;
#pragma unroll
            for (int j = 0; j < BB; ++j) {
                const float4 sv = *reinterpret_cast<const float4*>(&s_l[j][kk]);
                acc[j] += w0 * (double)sv.x + w1 * (double)sv.y
                        + w2 * (double)sv.z + w3 * (double)sv.w;
            }
        }
    }

#pragma unroll
    for (int j = 0; j < BB; ++j)
        partial[((size_t)blockIdx.y * BB + j) * NN + n] = acc[j];
}

// ---------------- LIF update kernel ----------------
__global__ __launch_bounds__(256) void upd64_kernel(
    const float* __restrict__ ext_exc,   // [T][BB][NE]
    const float* __restrict__ ext_inh,   // [T][BB][NI]
    const double* __restrict__ partial,  // [G][BB][NN]
    double* __restrict__ v,              // [BB][NN]
    float* __restrict__ s,               // [BB][NN]
    float* __restrict__ out,             // [T][BB][NN]
    int t, int G)
{
    const int idx = blockIdx.x * 256 + threadIdx.x;   // < BB*NN
    const int b = idx / NN;
    const int n = idx - b * NN;

    const float ext = (n < NE)
        ? ext_exc[((size_t)t * BB + b) * NE + n]
        : ext_inh[((size_t)t * BB + b) * NI + (n - NE)];

    double acc = (double)ext;
    for (int g = 0; g < G; ++g)
        acc += partial[((size_t)g * BB + b) * NN + n];

    const double vv = v[idx] * 0.9 + acc;
    const double sp = (vv > 1.0) ? 1.0 : 0.0;
    out[((size_t)t * BB + b) * NN + n] = (float)sp;
    v[idx] = vv * (1.0 - sp);
    s[idx] = (float)sp;
}

extern "C" void kernel_launch(void* const* d_in, const int* in_sizes, int n_in,
                              void* d_out, int out_size, void* d_ws, size_t ws_size,
                              hipStream_t stream) {
    const float* ext_exc = (const float*)d_in[0];
    const float* ext_inh = (const float*)d_in[1];
    const float* W_ee = (const float*)d_in[2];
    const float* W_ei = (const float*)d_in[3];
    const float* W_ie = (const float*)d_in[4];
    const float* W_ii = (const float*)d_in[5];
    float* out = (float*)d_out;

    const int T = in_sizes[0] / (BB * NE);   // 64

    const size_t SN = (size_t)BB * NN;       // 163840
    double* v = (double*)d_ws;
    float* sbuf = (float*)(v + SN);
    double* partial = (double*)(sbuf + SN);  // offset 12*SN bytes, 8B-aligned
    const size_t stateBytes = 12 * SN;       // v (8B) + s (4B)

    // pick largest k-split G whose fp64 partial fits the workspace
    int G = NCHUNKS;
    while (G > 1 && stateBytes + (size_t)G * SN * 8 > ws_size) G >>= 1;

    hipMemsetAsync(d_ws, 0, stateBytes, stream);   // v = 0, s = 0

    for (int t = 0; t < T; ++t) {
        switch (G) {
            case 32: mv64_kernel<1> <<<dim3(NN/256, 32), 256, 0, stream>>>(W_ee, W_ei, W_ie, W_ii, sbuf, partial); break;
            case 16: mv64_kernel<2> <<<dim3(NN/256, 16), 256, 0, stream>>>(W_ee, W_ei, W_ie, W_ii, sbuf, partial); break;
            case 8:  mv64_kernel<4> <<<dim3(NN/256,  8), 256, 0, stream>>>(W_ee, W_ei, W_ie, W_ii, sbuf, partial); break;
            case 4:  mv64_kernel<8> <<<dim3(NN/256,  4), 256, 0, stream>>>(W_ee, W_ei, W_ie, W_ii, sbuf, partial); break;
            case 2:  mv64_kernel<16><<<dim3(NN/256,  2), 256, 0, stream>>>(W_ee, W_ei, W_ie, W_ii, sbuf, partial); break;
            default: mv64_kernel<32><<<dim3(NN/256,  1), 256, 0, stream>>>(W_ee, W_ei, W_ie, W_ii, sbuf, partial); break;
        }
        upd64_kernel<<<(int)(SN / 256), 256, 0, stream>>>(
            ext_exc, ext_inh, partial, v, sbuf, out, t, G);
    }
}